// Round 7
// baseline (151.856 us; speedup 1.0000x reference)
//
#include <hip/hip_runtime.h>

#define NF 32       // IN_FEATS == OUT_FEATS == 32
#define RB 256      // nodes per bucket -> 391 buckets
#define RBITS 8
#define CAPE 5632   // per-bucket edge capacity (mean 4096, sigma 64, +24 sigma slack)
#define CAPEP 9728  // padded per-bucket csrc stride: CAPE + RB*16 (worst-case padding)
#define P1T 512     // partition threads
#define P1E 8       // edges per thread (tile = 4096 -> 391 blocks, all CUs busy)
#define PT 512      // place threads
#define PE ((CAPE + PT - 1) / PT)  // 11 edges per thread
#define NBMAX 512
#define GT 256      // gather threads: 8 nodes x 32 lanes

// ---- Pass 1: bucket-partition edges by dst>>RBITS into ebuf (packed ldst<<17 | src) ----
// LDS histogram gives each edge a local rank; ONE global atomic per bucket reserves a
// contiguous run. P1E=8 -> 391 blocks so every CU holds work (was 196 blocks).
__global__ __launch_bounds__(P1T) void partition_kernel(
    const int* __restrict__ src, const int* __restrict__ dst,
    int* __restrict__ gcount, unsigned int* __restrict__ ebuf,
    float* __restrict__ xprime, int n_edges, int n_nodes, int nb) {
    __shared__ int hist[NBMAX];
    __shared__ int gbase[NBMAX];
    int t = threadIdx.x;
    hist[t] = 0;
    // zero sentinel row xprime[n_nodes] (workspace is re-poisoned every launch)
    if (blockIdx.x == 0 && t < NF) xprime[(size_t)n_nodes * NF + t] = 0.f;
    __syncthreads();
    int tile0 = blockIdx.x * (P1T * P1E);
    unsigned int pk[P1E];
    int br[P1E];
#pragma unroll
    for (int k = 0; k < P1E; k++) {
        int i = tile0 + k * P1T + t;
        int b = -1, r = 0;
        unsigned int p = 0;
        if (i < n_edges) {
            int d = dst[i];
            int s = src[i];
            b = d >> RBITS;
            p = ((unsigned int)(d & (RB - 1)) << 17) | (unsigned int)s;  // src < 2^17
            r = atomicAdd(&hist[b], 1);  // LDS atomic: local rank
        }
        pk[k] = p;
        br[k] = (b << 16) | r;  // b==-1 stays negative after >>16 (r < 4096 fits 16 bits)
    }
    __syncthreads();
    if (t < nb) gbase[t] = atomicAdd(&gcount[t], hist[t]);  // one global atomic per bucket
    __syncthreads();
#pragma unroll
    for (int k = 0; k < P1E; k++) {
        int b = br[k] >> 16;
        if (b >= 0) {
            int u = gbase[b] + (br[k] & 0xFFFF);
            if (u < CAPE) ebuf[(size_t)b * CAPE + u] = pk[k];  // guard: memory-safe on overflow
        }
    }
}

// ---- Pass 2: per-bucket counting sort into PADDED per-node lists (multiple of 16,
// sentinel = n_nodes -> zero row), written at FIXED stride b*CAPEP (no bucket-base
// scan needed at all). rowinfo packs (padded_len/16 << 22) | beg  (beg < 3.81M < 2^22,
// len/16 <= 592 < 2^10). Also emits isd and the x' = x*isd prescale.
__global__ __launch_bounds__(PT) void place_kernel(
    const int* __restrict__ gcount, const unsigned int* __restrict__ ebuf,
    const float* __restrict__ x, float* __restrict__ xprime,
    int* __restrict__ csrc, unsigned int* __restrict__ rowinfo, float* __restrict__ isd,
    int n_nodes, int nb) {
    __shared__ int hist[RB];      // true per-node counts (= deg)
    __shared__ int lofs[RB];      // inclusive scan of PADDED counts
    __shared__ int sorted[CAPEP]; // 38.9 KB staging
    int t = threadIdx.x;
    int b = blockIdx.x;

    if (t < RB) hist[t] = 0;
    __syncthreads();
    int c = min(gcount[b], CAPE);
    int base = b * CAPEP;

    const unsigned int* eb = ebuf + (size_t)b * CAPE;
    unsigned int pk[PE];
    int pr[PE];
#pragma unroll
    for (int k = 0; k < PE; k++) {  // coalesced load + local rank per node
        int i = k * PT + t;
        unsigned int p = 0;
        int r = -1;
        if (i < c) {
            p = eb[i];
            r = atomicAdd(&hist[p >> 17], 1);
        }
        pk[k] = p;
        pr[k] = r;
    }
    __syncthreads();
    if (t < RB) lofs[t] = (hist[t] + 15) & ~15;  // padded count
    __syncthreads();
    for (int d = 1; d < RB; d <<= 1) {  // inclusive scan of padded counts
        int y = 0;
        if (t < RB && t >= d) y = lofs[t - d];
        __syncthreads();
        if (t < RB) lofs[t] += y;
        __syncthreads();
    }
    int pc_total = lofs[RB - 1];  // <= CAPE + RB*15 < CAPEP
    for (int i = t; i < pc_total; i += PT) sorted[i] = n_nodes;  // sentinel fill
    __syncthreads();
#pragma unroll
    for (int k = 0; k < PE; k++) {  // scatter to per-node-sorted order in LDS
        if (pr[k] >= 0) {
            int ld = (int)(pk[k] >> 17);
            int pc = (hist[ld] + 15) & ~15;
            sorted[lofs[ld] - pc + pr[k]] = (int)(pk[k] & 0x1FFFF);
        }
    }
    __syncthreads();
    for (int i = t; i < pc_total; i += PT) csrc[base + i] = sorted[i];  // coalesced out
    if (t < RB) {
        int node = (b << RBITS) + t;
        if (node < n_nodes) {
            int pc = (hist[t] + 15) & ~15;
            rowinfo[node] = ((unsigned int)(pc >> 4) << 22) |
                            (unsigned int)(base + lofs[t] - pc);
            isd[node] = rsqrtf((float)(hist[t] + 1));  // +1 self-loop
        }
    }
    // fused prescale: x'[node] = x[node] * isd[node] for this bucket's rows.
    const float4* x4 = (const float4*)x;
    float4* xp4 = (float4*)xprime;
    for (int i = t; i < RB * 8; i += PT) {
        int ld = i >> 3;
        int node = (b << RBITS) + ld;
        if (node < n_nodes) {
            float si = rsqrtf((float)(hist[ld] + 1));
            float4 xv = x4[(size_t)node * 8 + (i & 7)];
            float4 r;
            r.x = xv.x * si; r.y = xv.y * si; r.z = xv.z * si; r.w = xv.w * si;
            xp4[(size_t)node * 8 + (i & 7)] = r;
        }
    }
}

// ---- Pass 3: mask-free node-parallel float4 gather + fused project + finalize ---------
// Edge lists are padded to x16 with sentinel rows (zero, L1-resident), so the inner
// loop is branchless: fixed 16-edge chunks, 4 independent dwordx4 (16 random lines) per
// chunk, 2-chunk unroll (8 loads, 32 lines) for longer lists. Fold shfl_down(8,16);
// epilogue applies 32x32 W^T once per node (linearity), fused bias+relu.
__global__ __launch_bounds__(GT) void gather_quad(
    const unsigned int* __restrict__ rowinfo, const int* __restrict__ csrc,
    const float4* __restrict__ xp4, const float* __restrict__ isd,
    const float* __restrict__ W, const float* __restrict__ bias,
    float* __restrict__ out, int n_nodes) {
    __shared__ float sWt[NF * NF];   // sWt[i*32+o] = W[o*32+i]
    __shared__ float xbuf[8 * NF];   // per-group aggregated feature vector
    int t = threadIdx.x;
    for (int k = t; k < NF * NF; k += GT) sWt[k] = W[(k & 31) * NF + (k >> 5)];
    __syncthreads();
    int g = t >> 5, o = t & 31;
    int node = blockIdx.x * 8 + g;
    if (node >= n_nodes) return;
    unsigned int u = rowinfo[node];
    int beg = (int)(u & 0x3FFFFF);
    int it = (int)(u >> 22);  // number of 16-edge chunks
    int q = o >> 3;  // edge slot within a quad (0..3)
    int f = o & 7;   // float4 slot within a row (0..7)
    float ax = 0.f, ay = 0.f, az = 0.f, aw = 0.f;
    int k = 0;
    for (; k + 1 < it; k += 2) {  // 2 chunks: 8 independent dwordx4 = 32 lines in flight
        int ia = csrc[beg + k * 16 + (o & 15)];
        int ib = csrc[beg + k * 16 + 16 + (o & 15)];
        int a0 = __shfl(ia, q, 32), a1 = __shfl(ia, q + 4, 32);
        int a2 = __shfl(ia, q + 8, 32), a3 = __shfl(ia, q + 12, 32);
        int b0 = __shfl(ib, q, 32), b1 = __shfl(ib, q + 4, 32);
        int b2 = __shfl(ib, q + 8, 32), b3 = __shfl(ib, q + 12, 32);
        float4 wa0 = xp4[(size_t)a0 * 8 + f];
        float4 wa1 = xp4[(size_t)a1 * 8 + f];
        float4 wa2 = xp4[(size_t)a2 * 8 + f];
        float4 wa3 = xp4[(size_t)a3 * 8 + f];
        float4 wb0 = xp4[(size_t)b0 * 8 + f];
        float4 wb1 = xp4[(size_t)b1 * 8 + f];
        float4 wb2 = xp4[(size_t)b2 * 8 + f];
        float4 wb3 = xp4[(size_t)b3 * 8 + f];
        ax += wa0.x; ay += wa0.y; az += wa0.z; aw += wa0.w;
        ax += wa1.x; ay += wa1.y; az += wa1.z; aw += wa1.w;
        ax += wa2.x; ay += wa2.y; az += wa2.z; aw += wa2.w;
        ax += wa3.x; ay += wa3.y; az += wa3.z; aw += wa3.w;
        ax += wb0.x; ay += wb0.y; az += wb0.z; aw += wb0.w;
        ax += wb1.x; ay += wb1.y; az += wb1.z; aw += wb1.w;
        ax += wb2.x; ay += wb2.y; az += wb2.z; aw += wb2.w;
        ax += wb3.x; ay += wb3.y; az += wb3.z; aw += wb3.w;
    }
    for (; k < it; k++) {  // tail chunk: 4 independent dwordx4
        int ia = csrc[beg + k * 16 + (o & 15)];
        int a0 = __shfl(ia, q, 32), a1 = __shfl(ia, q + 4, 32);
        int a2 = __shfl(ia, q + 8, 32), a3 = __shfl(ia, q + 12, 32);
        float4 wa0 = xp4[(size_t)a0 * 8 + f];
        float4 wa1 = xp4[(size_t)a1 * 8 + f];
        float4 wa2 = xp4[(size_t)a2 * 8 + f];
        float4 wa3 = xp4[(size_t)a3 * 8 + f];
        ax += wa0.x; ay += wa0.y; az += wa0.z; aw += wa0.w;
        ax += wa1.x; ay += wa1.y; az += wa1.z; aw += wa1.w;
        ax += wa2.x; ay += wa2.y; az += wa2.z; aw += wa2.w;
        ax += wa3.x; ay += wa3.y; az += wa3.z; aw += wa3.w;
    }
    // fold the 4 edge-slots (lanes o, o+8, o+16, o+24 share the same feature block)
    ax += __shfl_down(ax, 8, 32); ay += __shfl_down(ay, 8, 32);
    az += __shfl_down(az, 8, 32); aw += __shfl_down(aw, 8, 32);
    ax += __shfl_down(ax, 16, 32); ay += __shfl_down(ay, 16, 32);
    az += __shfl_down(az, 16, 32); aw += __shfl_down(aw, 16, 32);
    if (q == 0) {  // lanes 0..7 of the group hold the totals; add self-loop row
        float4 sv = xp4[(size_t)node * 8 + f];
        float4 r;
        r.x = ax + sv.x; r.y = ay + sv.y; r.z = az + sv.z; r.w = aw + sv.w;
        ((float4*)xbuf)[g * 8 + f] = r;  // same wave writes then reads: ordered
    }
    float r = 0.f;
#pragma unroll
    for (int i2 = 0; i2 < NF; i2++) r = fmaf(xbuf[g * NF + i2], sWt[i2 * NF + o], r);
    float v = fmaf(r, isd[node], bias[o]);
    out[(size_t)node * NF + o] = fmaxf(v, 0.f);
}

extern "C" void kernel_launch(void* const* d_in, const int* in_sizes, int n_in,
                              void* d_out, int out_size, void* d_ws, size_t ws_size,
                              hipStream_t stream) {
    const float* feature = (const float*)d_in[0];
    const int*   src     = (const int*)d_in[1];
    const int*   dst     = (const int*)d_in[2];
    const float* W       = (const float*)d_in[3];
    const float* bias    = (const float*)d_in[4];
    float* out = (float*)d_out;

    int n_nodes = in_sizes[0] / NF;
    int n_edges = in_sizes[1];
    int nb = (n_nodes + RB - 1) / RB;  // 391 buckets

    char* ws = (char*)d_ws;
    size_t off = 0;
    unsigned int* ebuf = (unsigned int*)(ws + off);
    off += (((size_t)nb * CAPE * 4) + 255) & ~(size_t)255;
    int* csrc = (int*)(ws + off);
    off += (((size_t)nb * CAPEP * 4) + 255) & ~(size_t)255;
    unsigned int* rowinfo = (unsigned int*)(ws + off);
    off += ((size_t)n_nodes * 4 + 255) & ~(size_t)255;
    float* isd = (float*)(ws + off);
    off += ((size_t)n_nodes * 4 + 255) & ~(size_t)255;
    float* xprime = (float*)(ws + off);
    off += ((size_t)(n_nodes + 1) * NF * 4 + 255) & ~(size_t)255;  // +1 sentinel zero row
    int* gcount = (int*)(ws + off);

    hipMemsetAsync(gcount, 0, NBMAX * 4, stream);

    int p1_grid = (n_edges + P1T * P1E - 1) / (P1T * P1E);
    partition_kernel<<<p1_grid, P1T, 0, stream>>>(src, dst, gcount, ebuf, xprime,
                                                  n_edges, n_nodes, nb);

    place_kernel<<<nb, PT, 0, stream>>>(gcount, ebuf, feature, xprime, csrc, rowinfo, isd,
                                        n_nodes, nb);

    gather_quad<<<(n_nodes + 7) / 8, GT, 0, stream>>>(rowinfo, csrc, (const float4*)xprime,
                                                      isd, W, bias, out, n_nodes);
}

// Round 8
// 146.067 us; speedup vs baseline: 1.0396x; 1.0396x over previous
//
#include <hip/hip_runtime.h>

#define NF 32       // IN_FEATS == OUT_FEATS == 32
#define RB 256      // nodes per bucket -> 391 buckets
#define RBITS 8
#define CAPE 5632   // per-bucket edge capacity (mean 4096, sigma 64, +24 sigma slack)
#define P1T 512     // partition threads
#define P1E 8       // edges per thread (tile = 4096 -> 391 blocks, all CUs busy)
#define PT 512      // place threads
#define PE ((CAPE + PT - 1) / PT)  // 11 edges per thread
#define NBMAX 512
#define GT 256      // gather threads: 8 nodes x 32 lanes

typedef _Float16 half4v __attribute__((ext_vector_type(4)));  // 8 B
typedef _Float16 half8v __attribute__((ext_vector_type(8)));  // 16 B

// ---- Pass 1: bucket-partition edges by dst>>RBITS into ebuf (packed ldst<<17 | src) ----
// LDS histogram gives each edge a local rank; ONE global atomic per bucket reserves a
// contiguous run; 391 blocks so every CU holds work.
__global__ __launch_bounds__(P1T) void partition_kernel(
    const int* __restrict__ src, const int* __restrict__ dst,
    int* __restrict__ gcount, unsigned int* __restrict__ ebuf, int n_edges, int nb) {
    __shared__ int hist[NBMAX];
    __shared__ int gbase[NBMAX];
    int t = threadIdx.x;
    hist[t] = 0;
    __syncthreads();
    int tile0 = blockIdx.x * (P1T * P1E);
    unsigned int pk[P1E];
    int br[P1E];
#pragma unroll
    for (int k = 0; k < P1E; k++) {
        int i = tile0 + k * P1T + t;
        int b = -1, r = 0;
        unsigned int p = 0;
        if (i < n_edges) {
            int d = dst[i];
            int s = src[i];
            b = d >> RBITS;
            p = ((unsigned int)(d & (RB - 1)) << 17) | (unsigned int)s;  // src < 2^17
            r = atomicAdd(&hist[b], 1);  // LDS atomic: local rank
        }
        pk[k] = p;
        br[k] = (b << 16) | r;  // b==-1 stays negative after >>16 (r < 4096 fits 16 bits)
    }
    __syncthreads();
    if (t < nb) gbase[t] = atomicAdd(&gcount[t], hist[t]);  // one global atomic per bucket
    __syncthreads();
#pragma unroll
    for (int k = 0; k < P1E; k++) {
        int b = br[k] >> 16;
        if (b >= 0) {
            int u = gbase[b] + (br[k] & 0xFFFF);
            if (u < CAPE) ebuf[(size_t)b * CAPE + u] = pk[k];  // guard: memory-safe on overflow
        }
    }
}

// ---- Pass 2: per-bucket counting sort -> csrc at FIXED stride b*CAPE (no global
// compaction, no bucket-base scan), rowinfo = (beg, cnt) per node, isd, and the
// fp16 prescale x' = x*isd (row = 64 B: halves gather line traffic, and the 6.4 MB
// buffer nearly fits per-XCD L2). Block 0 zeroes the sentinel row x'[n_nodes].
__global__ __launch_bounds__(PT) void place_kernel(
    const int* __restrict__ gcount, const unsigned int* __restrict__ ebuf,
    const float* __restrict__ x, _Float16* __restrict__ xprime,
    int* __restrict__ csrc, int2* __restrict__ rowinfo, float* __restrict__ isd,
    int n_nodes, int nb) {
    __shared__ int hist[RB];      // per-node counts (= deg)
    __shared__ int lofs[RB];      // inclusive scan of counts
    __shared__ int sorted[CAPE];  // 22.5 KB staging
    int t = threadIdx.x;
    int b = blockIdx.x;

    if (t < RB) hist[t] = 0;
    // sentinel zero row (fp16 zeros == zero bits); workspace is re-poisoned each launch
    if (b == 0 && t < 16) ((float*)xprime)[(size_t)n_nodes * 16 + t] = 0.f;
    __syncthreads();
    int c = min(gcount[b], CAPE);
    int base = b * CAPE;

    const unsigned int* eb = ebuf + (size_t)b * CAPE;
    unsigned int pk[PE];
    int pr[PE];
#pragma unroll
    for (int k = 0; k < PE; k++) {  // coalesced load + local rank per node
        int i = k * PT + t;
        unsigned int p = 0;
        int r = -1;
        if (i < c) {
            p = eb[i];
            r = atomicAdd(&hist[p >> 17], 1);
        }
        pk[k] = p;
        pr[k] = r;
    }
    __syncthreads();
    if (t < RB) lofs[t] = hist[t];
    __syncthreads();
    for (int d = 1; d < RB; d <<= 1) {  // inclusive scan of per-node counts
        int y = 0;
        if (t < RB && t >= d) y = lofs[t - d];
        __syncthreads();
        if (t < RB) lofs[t] += y;
        __syncthreads();
    }
#pragma unroll
    for (int k = 0; k < PE; k++) {  // scatter to per-node-sorted order in LDS
        if (pr[k] >= 0) {
            int ld = (int)(pk[k] >> 17);
            sorted[lofs[ld] - hist[ld] + pr[k]] = (int)(pk[k] & 0x1FFFF);
        }
    }
    __syncthreads();
    for (int i = t; i < c; i += PT) csrc[base + i] = sorted[i];  // coalesced out
    if (t < RB) {
        int node = (b << RBITS) + t;
        if (node < n_nodes) {
            rowinfo[node] = make_int2(base + lofs[t] - hist[t], hist[t]);
            isd[node] = rsqrtf((float)(hist[t] + 1));  // +1 self-loop
        }
    }
    // fused fp16 prescale: x'[node] = (half)(x[node] * isd[node]) for this bucket's rows
    const float4* x4 = (const float4*)x;
    half4v* xp4 = (half4v*)xprime;
    for (int i = t; i < RB * 8; i += PT) {
        int ld = i >> 3;
        int node = (b << RBITS) + ld;
        if (node < n_nodes) {
            float si = rsqrtf((float)(hist[ld] + 1));
            float4 xv = x4[(size_t)node * 8 + (i & 7)];
            half4v hv;
            hv[0] = (_Float16)(xv.x * si); hv[1] = (_Float16)(xv.y * si);
            hv[2] = (_Float16)(xv.z * si); hv[3] = (_Float16)(xv.w * si);
            xp4[(size_t)node * 8 + (i & 7)] = hv;
        }
    }
}

// ---- Pass 3: node-parallel fp16 gather + fused project + finalize ---------------------
// 32-lane group = 8 edges x 4 lanes (16 B each): one dwordx4 touches 8 random 64 B
// rows; 4 independent loads per 32-edge stride = 32 lines in flight per group.
// Out-of-range edge slots clamp to the sentinel zero row (L1-resident). f32
// accumulate; fold across the 8 edge-slots with shfl_down(4,8,16); epilogue applies
// the 32x32 W^T once per node (linearity), fused bias+relu.
__global__ __launch_bounds__(GT) void gather_half(
    const int2* __restrict__ rowinfo, const int* __restrict__ csrc,
    const half8v* __restrict__ xp, const float* __restrict__ isd,
    const float* __restrict__ W, const float* __restrict__ bias,
    float* __restrict__ out, int n_nodes) {
    __shared__ float sWt[NF * NF];   // sWt[i*32+o] = W[o*32+i]
    __shared__ float xbuf[8 * NF];   // per-group aggregated feature vector
    int t = threadIdx.x;
    for (int k = t; k < NF * NF; k += GT) sWt[k] = W[(k & 31) * NF + (k >> 5)];
    __syncthreads();
    int g = t >> 5, o = t & 31;
    int node = blockIdx.x * 8 + g;
    if (node >= n_nodes) return;
    int2 ri = rowinfo[node];
    int beg = ri.x, cnt = ri.y;
    int q = o >> 2;  // edge slot within the stride (0..7)
    int f = o & 3;   // 16 B slot within a row (0..3)
    float a0 = 0.f, a1 = 0.f, a2 = 0.f, a3 = 0.f;
    float a4 = 0.f, a5 = 0.f, a6 = 0.f, a7 = 0.f;
    for (int s = 0; s < cnt; s += 32) {
        int i = s + o;
        int idx = (i < cnt) ? csrc[beg + i] : n_nodes;  // coalesced; OOR -> sentinel row
        int e0 = __shfl(idx, q, 32);
        int e1 = __shfl(idx, 8 + q, 32);
        int e2 = __shfl(idx, 16 + q, 32);
        int e3 = __shfl(idx, 24 + q, 32);
        half8v w0 = xp[(size_t)e0 * 4 + f];   // 4 independent dwordx4
        half8v w1 = xp[(size_t)e1 * 4 + f];
        half8v w2 = xp[(size_t)e2 * 4 + f];
        half8v w3 = xp[(size_t)e3 * 4 + f];
        a0 += (float)w0[0] + (float)w1[0] + (float)w2[0] + (float)w3[0];
        a1 += (float)w0[1] + (float)w1[1] + (float)w2[1] + (float)w3[1];
        a2 += (float)w0[2] + (float)w1[2] + (float)w2[2] + (float)w3[2];
        a3 += (float)w0[3] + (float)w1[3] + (float)w2[3] + (float)w3[3];
        a4 += (float)w0[4] + (float)w1[4] + (float)w2[4] + (float)w3[4];
        a5 += (float)w0[5] + (float)w1[5] + (float)w2[5] + (float)w3[5];
        a6 += (float)w0[6] + (float)w1[6] + (float)w2[6] + (float)w3[6];
        a7 += (float)w0[7] + (float)w1[7] + (float)w2[7] + (float)w3[7];
    }
    // fold the 8 edge-slots (lanes f, f+4, ..., f+28 share the same 16 B feature slot)
    a0 += __shfl_down(a0, 4, 32); a1 += __shfl_down(a1, 4, 32);
    a2 += __shfl_down(a2, 4, 32); a3 += __shfl_down(a3, 4, 32);
    a4 += __shfl_down(a4, 4, 32); a5 += __shfl_down(a5, 4, 32);
    a6 += __shfl_down(a6, 4, 32); a7 += __shfl_down(a7, 4, 32);
    a0 += __shfl_down(a0, 8, 32); a1 += __shfl_down(a1, 8, 32);
    a2 += __shfl_down(a2, 8, 32); a3 += __shfl_down(a3, 8, 32);
    a4 += __shfl_down(a4, 8, 32); a5 += __shfl_down(a5, 8, 32);
    a6 += __shfl_down(a6, 8, 32); a7 += __shfl_down(a7, 8, 32);
    a0 += __shfl_down(a0, 16, 32); a1 += __shfl_down(a1, 16, 32);
    a2 += __shfl_down(a2, 16, 32); a3 += __shfl_down(a3, 16, 32);
    a4 += __shfl_down(a4, 16, 32); a5 += __shfl_down(a5, 16, 32);
    a6 += __shfl_down(a6, 16, 32); a7 += __shfl_down(a7, 16, 32);
    if (q == 0) {  // lanes 0..3 hold totals for features [f*8, f*8+8); add self-loop
        half8v sv = xp[(size_t)node * 4 + f];
        float* xb = xbuf + g * NF + f * 8;
        xb[0] = a0 + (float)sv[0]; xb[1] = a1 + (float)sv[1];
        xb[2] = a2 + (float)sv[2]; xb[3] = a3 + (float)sv[3];
        xb[4] = a4 + (float)sv[4]; xb[5] = a5 + (float)sv[5];
        xb[6] = a6 + (float)sv[6]; xb[7] = a7 + (float)sv[7];
    }
    // same 32 lanes (one wave-half) wrote xbuf then read it: in-wave ordered
    float r = 0.f;
#pragma unroll
    for (int i2 = 0; i2 < NF; i2++) r = fmaf(xbuf[g * NF + i2], sWt[i2 * NF + o], r);
    float v = fmaf(r, isd[node], bias[o]);
    out[(size_t)node * NF + o] = fmaxf(v, 0.f);
}

extern "C" void kernel_launch(void* const* d_in, const int* in_sizes, int n_in,
                              void* d_out, int out_size, void* d_ws, size_t ws_size,
                              hipStream_t stream) {
    const float* feature = (const float*)d_in[0];
    const int*   src     = (const int*)d_in[1];
    const int*   dst     = (const int*)d_in[2];
    const float* W       = (const float*)d_in[3];
    const float* bias    = (const float*)d_in[4];
    float* out = (float*)d_out;

    int n_nodes = in_sizes[0] / NF;
    int n_edges = in_sizes[1];
    int nb = (n_nodes + RB - 1) / RB;  // 391 buckets

    char* ws = (char*)d_ws;
    size_t off = 0;
    unsigned int* ebuf = (unsigned int*)(ws + off);
    off += (((size_t)nb * CAPE * 4) + 255) & ~(size_t)255;
    int* csrc = (int*)(ws + off);
    off += (((size_t)nb * CAPE * 4) + 255) & ~(size_t)255;
    int2* rowinfo = (int2*)(ws + off);
    off += ((size_t)n_nodes * 8 + 255) & ~(size_t)255;
    float* isd = (float*)(ws + off);
    off += ((size_t)n_nodes * 4 + 255) & ~(size_t)255;
    _Float16* xprime = (_Float16*)(ws + off);
    off += ((size_t)(n_nodes + 1) * NF * 2 + 255) & ~(size_t)255;  // +1 sentinel zero row
    int* gcount = (int*)(ws + off);

    hipMemsetAsync(gcount, 0, NBMAX * 4, stream);

    int p1_grid = (n_edges + P1T * P1E - 1) / (P1T * P1E);
    partition_kernel<<<p1_grid, P1T, 0, stream>>>(src, dst, gcount, ebuf, n_edges, nb);

    place_kernel<<<nb, PT, 0, stream>>>(gcount, ebuf, feature, xprime, csrc, rowinfo, isd,
                                        n_nodes, nb);

    gather_half<<<(n_nodes + 7) / 8, GT, 0, stream>>>(rowinfo, csrc, (const half8v*)xprime,
                                                      isd, W, bias, out, n_nodes);
}

// Round 9
// 139.352 us; speedup vs baseline: 1.0897x; 1.0482x over previous
//
#include <hip/hip_runtime.h>

#define NF 32       // IN_FEATS == OUT_FEATS == 32
#define RB 256      // nodes per bucket -> 391 buckets
#define RBITS 8
#define CAPE 5632   // per-bucket edge capacity (mean 4096, sigma 64, +24 sigma slack)
#define P1T 512     // partition threads
#define P1E 8       // edges per thread (tile = 4096 -> 391 blocks, all CUs busy)
#define PT 512      // place threads
#define PE ((CAPE + PT - 1) / PT)  // 11 edges per thread
#define NBMAX 512
#define GT 256      // gather threads: 8 groups x 32 lanes
#define GB 2048     // gather blocks: 8 per CU -> full residency, persistent grid-stride

typedef _Float16 half4v __attribute__((ext_vector_type(4)));  // 8 B
typedef _Float16 half8v __attribute__((ext_vector_type(8)));  // 16 B

// ---- Pass 1: bucket-partition edges by dst>>RBITS into ebuf (packed ldst<<17 | src) ----
// LDS histogram gives each edge a local rank; ONE global atomic per bucket reserves a
// contiguous run; 391 blocks so every CU holds work.
__global__ __launch_bounds__(P1T) void partition_kernel(
    const int* __restrict__ src, const int* __restrict__ dst,
    int* __restrict__ gcount, unsigned int* __restrict__ ebuf, int n_edges, int nb) {
    __shared__ int hist[NBMAX];
    __shared__ int gbase[NBMAX];
    int t = threadIdx.x;
    hist[t] = 0;
    __syncthreads();
    int tile0 = blockIdx.x * (P1T * P1E);
    unsigned int pk[P1E];
    int br[P1E];
#pragma unroll
    for (int k = 0; k < P1E; k++) {
        int i = tile0 + k * P1T + t;
        int b = -1, r = 0;
        unsigned int p = 0;
        if (i < n_edges) {
            int d = dst[i];
            int s = src[i];
            b = d >> RBITS;
            p = ((unsigned int)(d & (RB - 1)) << 17) | (unsigned int)s;  // src < 2^17
            r = atomicAdd(&hist[b], 1);  // LDS atomic: local rank
        }
        pk[k] = p;
        br[k] = (b << 16) | r;  // b==-1 stays negative after >>16 (r < 4096 fits 16 bits)
    }
    __syncthreads();
    if (t < nb) gbase[t] = atomicAdd(&gcount[t], hist[t]);  // one global atomic per bucket
    __syncthreads();
#pragma unroll
    for (int k = 0; k < P1E; k++) {
        int b = br[k] >> 16;
        if (b >= 0) {
            int u = gbase[b] + (br[k] & 0xFFFF);
            if (u < CAPE) ebuf[(size_t)b * CAPE + u] = pk[k];  // guard: memory-safe on overflow
        }
    }
}

// ---- Pass 2: per-bucket counting sort -> csrc at FIXED stride b*CAPE, rowinfo =
// (beg, cnt) per node, and the fp16 prescale x' = x*isd (row = 64 B). isd is NOT
// materialized: gather recomputes rsqrtf(cnt+1) from rowinfo. Block 0 zeroes the
// sentinel row x'[n_nodes].
__global__ __launch_bounds__(PT) void place_kernel(
    const int* __restrict__ gcount, const unsigned int* __restrict__ ebuf,
    const float* __restrict__ x, _Float16* __restrict__ xprime,
    int* __restrict__ csrc, int2* __restrict__ rowinfo, int n_nodes, int nb) {
    __shared__ int hist[RB];      // per-node counts (= deg)
    __shared__ int lofs[RB];      // inclusive scan of counts
    __shared__ int sorted[CAPE];  // 22.5 KB staging
    int t = threadIdx.x;
    int b = blockIdx.x;

    if (t < RB) hist[t] = 0;
    // sentinel zero row (fp16 zeros == zero bits); workspace is re-poisoned each launch
    if (b == 0 && t < 16) ((float*)xprime)[(size_t)n_nodes * 16 + t] = 0.f;
    __syncthreads();
    int c = min(gcount[b], CAPE);
    int base = b * CAPE;

    const unsigned int* eb = ebuf + (size_t)b * CAPE;
    unsigned int pk[PE];
    int pr[PE];
#pragma unroll
    for (int k = 0; k < PE; k++) {  // coalesced load + local rank per node
        int i = k * PT + t;
        unsigned int p = 0;
        int r = -1;
        if (i < c) {
            p = eb[i];
            r = atomicAdd(&hist[p >> 17], 1);
        }
        pk[k] = p;
        pr[k] = r;
    }
    __syncthreads();
    if (t < RB) lofs[t] = hist[t];
    __syncthreads();
    for (int d = 1; d < RB; d <<= 1) {  // inclusive scan of per-node counts
        int y = 0;
        if (t < RB && t >= d) y = lofs[t - d];
        __syncthreads();
        if (t < RB) lofs[t] += y;
        __syncthreads();
    }
#pragma unroll
    for (int k = 0; k < PE; k++) {  // scatter to per-node-sorted order in LDS
        if (pr[k] >= 0) {
            int ld = (int)(pk[k] >> 17);
            sorted[lofs[ld] - hist[ld] + pr[k]] = (int)(pk[k] & 0x1FFFF);
        }
    }
    __syncthreads();
    for (int i = t; i < c; i += PT) csrc[base + i] = sorted[i];  // coalesced out
    if (t < RB) {
        int node = (b << RBITS) + t;
        if (node < n_nodes) rowinfo[node] = make_int2(base + lofs[t] - hist[t], hist[t]);
    }
    // fused fp16 prescale: x'[node] = (half)(x[node] * isd[node]) for this bucket's rows
    const float4* x4 = (const float4*)x;
    half4v* xp4 = (half4v*)xprime;
    for (int i = t; i < RB * 8; i += PT) {
        int ld = i >> 3;
        int node = (b << RBITS) + ld;
        if (node < n_nodes) {
            float si = rsqrtf((float)(hist[ld] + 1));
            float4 xv = x4[(size_t)node * 8 + (i & 7)];
            half4v hv;
            hv[0] = (_Float16)(xv.x * si); hv[1] = (_Float16)(xv.y * si);
            hv[2] = (_Float16)(xv.z * si); hv[3] = (_Float16)(xv.w * si);
            xp4[(size_t)node * 8 + (i & 7)] = hv;
        }
    }
}

// ---- Pass 3: persistent grid-stride fp16 gather + fused project + finalize -----------
// 2048 blocks x 256 thr = 8 blocks/CU resident (32 waves/CU, vs 70% occupancy before).
// Each 32-lane group (8 edge-slots x 4 f-slots) walks nodes at grid stride and
// PREFETCHES the next node's rowinfo before the current gather loop: the fold +
// 32x32 projection VALU of node n hides the cold rowinfo/csrc latency of node n+1.
// si recomputed as rsqrtf(cnt+1) - no isd load. f32 accumulate; sentinel zero row
// absorbs out-of-range edge slots.
__global__ __launch_bounds__(GT) void gather_half(
    const int2* __restrict__ rowinfo, const int* __restrict__ csrc,
    const half8v* __restrict__ xp, const float* __restrict__ W,
    const float* __restrict__ bias, float* __restrict__ out, int n_nodes) {
    __shared__ float sWt[NF * NF];   // sWt[i*32+o] = W[o*32+i]
    __shared__ float xbuf[8 * NF];   // per-group aggregated feature vector
    int t = threadIdx.x;
    for (int k = t; k < NF * NF; k += GT) sWt[k] = W[(k & 31) * NF + (k >> 5)];
    __syncthreads();
    int g = t >> 5, o = t & 31;
    int q = o >> 2;  // edge slot within the stride (0..7)
    int f = o & 3;   // 16 B slot within a row (0..3)
    float bo = bias[o];
    int ngroups = GB * (GT / 32);
    int node = blockIdx.x * (GT / 32) + g;
    if (node >= n_nodes) return;
    int2 ri = rowinfo[node];
    while (true) {
        int nnext = node + ngroups;
        bool have_next = nnext < n_nodes;
        int2 ri_next;
        if (have_next) ri_next = rowinfo[nnext];  // prefetch: overlaps this node's work
        int beg = ri.x, cnt = ri.y;
        float si = rsqrtf((float)(cnt + 1));
        float a0 = 0.f, a1 = 0.f, a2 = 0.f, a3 = 0.f;
        float a4 = 0.f, a5 = 0.f, a6 = 0.f, a7 = 0.f;
        for (int s = 0; s < cnt; s += 32) {
            int i = s + o;
            int idx = (i < cnt) ? csrc[beg + i] : n_nodes;  // coalesced; OOR -> sentinel
            int e0 = __shfl(idx, q, 32);
            int e1 = __shfl(idx, 8 + q, 32);
            int e2 = __shfl(idx, 16 + q, 32);
            int e3 = __shfl(idx, 24 + q, 32);
            half8v w0 = xp[(size_t)e0 * 4 + f];   // 4 independent dwordx4: 32 rows/group
            half8v w1 = xp[(size_t)e1 * 4 + f];
            half8v w2 = xp[(size_t)e2 * 4 + f];
            half8v w3 = xp[(size_t)e3 * 4 + f];
            a0 += (float)w0[0] + (float)w1[0] + (float)w2[0] + (float)w3[0];
            a1 += (float)w0[1] + (float)w1[1] + (float)w2[1] + (float)w3[1];
            a2 += (float)w0[2] + (float)w1[2] + (float)w2[2] + (float)w3[2];
            a3 += (float)w0[3] + (float)w1[3] + (float)w2[3] + (float)w3[3];
            a4 += (float)w0[4] + (float)w1[4] + (float)w2[4] + (float)w3[4];
            a5 += (float)w0[5] + (float)w1[5] + (float)w2[5] + (float)w3[5];
            a6 += (float)w0[6] + (float)w1[6] + (float)w2[6] + (float)w3[6];
            a7 += (float)w0[7] + (float)w1[7] + (float)w2[7] + (float)w3[7];
        }
        // fold the 8 edge-slots (lanes f, f+4, ..., f+28 share the same 16 B slot)
        a0 += __shfl_down(a0, 4, 32); a1 += __shfl_down(a1, 4, 32);
        a2 += __shfl_down(a2, 4, 32); a3 += __shfl_down(a3, 4, 32);
        a4 += __shfl_down(a4, 4, 32); a5 += __shfl_down(a5, 4, 32);
        a6 += __shfl_down(a6, 4, 32); a7 += __shfl_down(a7, 4, 32);
        a0 += __shfl_down(a0, 8, 32); a1 += __shfl_down(a1, 8, 32);
        a2 += __shfl_down(a2, 8, 32); a3 += __shfl_down(a3, 8, 32);
        a4 += __shfl_down(a4, 8, 32); a5 += __shfl_down(a5, 8, 32);
        a6 += __shfl_down(a6, 8, 32); a7 += __shfl_down(a7, 8, 32);
        a0 += __shfl_down(a0, 16, 32); a1 += __shfl_down(a1, 16, 32);
        a2 += __shfl_down(a2, 16, 32); a3 += __shfl_down(a3, 16, 32);
        a4 += __shfl_down(a4, 16, 32); a5 += __shfl_down(a5, 16, 32);
        a6 += __shfl_down(a6, 16, 32); a7 += __shfl_down(a7, 16, 32);
        if (q == 0) {  // lanes 0..3 hold totals for features [f*8, f*8+8); add self-loop
            half8v sv = xp[(size_t)node * 4 + f];
            float* xb = xbuf + g * NF + f * 8;
            xb[0] = a0 + (float)sv[0]; xb[1] = a1 + (float)sv[1];
            xb[2] = a2 + (float)sv[2]; xb[3] = a3 + (float)sv[3];
            xb[4] = a4 + (float)sv[4]; xb[5] = a5 + (float)sv[5];
            xb[6] = a6 + (float)sv[6]; xb[7] = a7 + (float)sv[7];
        }
        // same 32 lanes (one wave-half) wrote xbuf then read it: in-wave ordered
        float r = 0.f;
#pragma unroll
        for (int i2 = 0; i2 < NF; i2++) r = fmaf(xbuf[g * NF + i2], sWt[i2 * NF + o], r);
        float v = fmaf(r, si, bo);
        out[(size_t)node * NF + o] = fmaxf(v, 0.f);
        if (!have_next) break;
        node = nnext;
        ri = ri_next;
    }
}

extern "C" void kernel_launch(void* const* d_in, const int* in_sizes, int n_in,
                              void* d_out, int out_size, void* d_ws, size_t ws_size,
                              hipStream_t stream) {
    const float* feature = (const float*)d_in[0];
    const int*   src     = (const int*)d_in[1];
    const int*   dst     = (const int*)d_in[2];
    const float* W       = (const float*)d_in[3];
    const float* bias    = (const float*)d_in[4];
    float* out = (float*)d_out;

    int n_nodes = in_sizes[0] / NF;
    int n_edges = in_sizes[1];
    int nb = (n_nodes + RB - 1) / RB;  // 391 buckets

    char* ws = (char*)d_ws;
    size_t off = 0;
    unsigned int* ebuf = (unsigned int*)(ws + off);
    off += (((size_t)nb * CAPE * 4) + 255) & ~(size_t)255;
    int* csrc = (int*)(ws + off);
    off += (((size_t)nb * CAPE * 4) + 255) & ~(size_t)255;
    int2* rowinfo = (int2*)(ws + off);
    off += ((size_t)n_nodes * 8 + 255) & ~(size_t)255;
    _Float16* xprime = (_Float16*)(ws + off);
    off += ((size_t)(n_nodes + 1) * NF * 2 + 255) & ~(size_t)255;  // +1 sentinel zero row
    int* gcount = (int*)(ws + off);

    hipMemsetAsync(gcount, 0, NBMAX * 4, stream);

    int p1_grid = (n_edges + P1T * P1E - 1) / (P1T * P1E);
    partition_kernel<<<p1_grid, P1T, 0, stream>>>(src, dst, gcount, ebuf, n_edges, nb);

    place_kernel<<<nb, PT, 0, stream>>>(gcount, ebuf, feature, xprime, csrc, rowinfo,
                                        n_nodes, nb);

    gather_half<<<GB, GT, 0, stream>>>(rowinfo, csrc, (const half8v*)xprime,
                                       W, bias, out, n_nodes);
}